// Round 11
// baseline (55.872 us; speedup 1.0000x reference)
//
#include <hip/hip_runtime.h>
#include <math.h>

constexpr int NB = 8, NC = 64, NO = 64, NH = 64, NW = 64, NA = 4, NKK = 9;

using f32x4 = __attribute__((ext_vector_type(4))) float;
using s16x8 = __attribute__((ext_vector_type(8))) short;
using u32x4 = __attribute__((ext_vector_type(4))) unsigned int;

// packed f32x2 -> bf16x2 (RNE), v_cvt_pk_bf16_f32 (no builtin on gfx950)
__device__ __forceinline__ unsigned int pk2(float lo, float hi) {
    unsigned int r;
    asm("v_cvt_pk_bf16_f32 %0, %1, %2" : "=v"(r) : "v"(lo), "v"(hi));
    return r;   // lo in bits[15:0], hi in bits[31:16]
}
__device__ __forceinline__ unsigned short f2bf(float f) {
    unsigned u = __builtin_bit_cast(unsigned, f);
    return (unsigned short)((u + 0x7fffu + ((u >> 16) & 1u)) >> 16);
}
__device__ __forceinline__ float bf2f(unsigned short s) {
    unsigned u = ((unsigned)s) << 16;
    return __builtin_bit_cast(float, u);
}

// Grid 512 = b(8) x hpair(32) x osub(2). Block 512 thr = 8 waves.
// Block tile: 2 h-rows x 64 w x 32 o (obase = osub*32).
// Wave wv: ofrag = wv&1 (16 o), ltile = wv>>1 -> hrow = ltile>>1, whalf = ltile&1; 2 n-tiles.
// MFMA A = W (rows=o), B = x (cols=w). D: row(o)=q*4+reg, col(w)=c0 -> coalesced stores.
// k-OUTER loop: one k per iteration (4 atoms staged together) -> 9 barriers, patch read 1x/k.
// launch_bounds 2nd arg is CUDA-style min BLOCKS/CU (R7/R8: (512,4)->64 VGPR->spill disaster).
__global__ __launch_bounds__(512, 2)
void acda_kernel(const float* __restrict__ x, const float* __restrict__ w_gen,
                 const float* __restrict__ b_gen, const float* __restrict__ pos_enc,
                 float* __restrict__ out)
{
    __shared__ unsigned short Xs[128 * 64];          // 16 KB [loc][c] bf16, XOR-swizzled
    __shared__ unsigned short Wb[2][4][32 * 64];     // 32 KB dbuf x 4 atoms [o_l][c] bf16, swizzled
    __shared__ unsigned short Patch[4 * 66 * 36];    // 19 KB [hhi][wwi][o_l(32)+pad4] bf16
    __shared__ float BiasL[36 * 32];                 // 4.6 KB [(k*4+a)][o_l]

    const int tid  = threadIdx.x;
    const int lane = tid & 63;
    const int wv   = tid >> 6;
    const int c0   = lane & 15, q = lane >> 4;
    const int ofrag = wv & 1;
    const int ltile = wv >> 1;
    const int hrow = ltile >> 1, whalf = ltile & 1;

    const int bx    = blockIdx.x;
    const int osub  = bx & 1;
    const int hp    = (bx >> 1) & 31;
    const int b     = bx >> 6;
    const int hbase = hp * 2;
    const int obase = osub * 32;

    const size_t xB = (size_t)b * NC * NH * NW;

    // ---- W staging, T14-split: loadW4 (global->reg, one k = 4 atoms) / writeW4 (cvt+ds_write) ----
    // thread -> (a = tid>>7, o_l = (tid>>2)&31, sj = tid&3 -> channels sj*16..+16)
    const int sa = tid >> 7, so = (tid >> 2) & 31, sj = tid & 3;
    const float* wsrc0 = w_gen + (size_t)(((obase + so) * 4 + sa) * 9) * NC + sj * 16;
    const int wb0 = sa * 4096 + so * 128 + (((sj * 2) * 16) ^ ((so & 7) << 4));
    const int wb1 = sa * 4096 + so * 128 + (((sj * 2 + 1) * 16) ^ ((so & 7) << 4));

    float4 wl[4];
    auto loadW4 = [&](int k) {
        const float4* p = reinterpret_cast<const float4*>(wsrc0 + (size_t)k * NC);
        wl[0] = p[0]; wl[1] = p[1]; wl[2] = p[2]; wl[3] = p[3];
    };
    auto writeW4 = [&](int nbuf) {
        u32x4 v0, v1;
        v0[0] = pk2(wl[0].x, wl[0].y); v0[1] = pk2(wl[0].z, wl[0].w);
        v0[2] = pk2(wl[1].x, wl[1].y); v0[3] = pk2(wl[1].z, wl[1].w);
        v1[0] = pk2(wl[2].x, wl[2].y); v1[1] = pk2(wl[2].z, wl[2].w);
        v1[2] = pk2(wl[3].x, wl[3].y); v1[3] = pk2(wl[3].z, wl[3].w);
        unsigned char* base = reinterpret_cast<unsigned char*>(&Wb[nbuf][0][0]);
        *reinterpret_cast<u32x4*>(base + wb0) = v0;
        *reinterpret_cast<u32x4*>(base + wb1) = v1;
    };

    loadW4(0);   // k=0 loads in flight; Xs/Patch/bias staging hides the latency

    // ---- stage Xs: x[b, c, hbase+hs, w] -> Xs[loc = hs*64+w][c] (bf16, swizzled) ----
    {
        const int w = lane, oct = wv;
        for (int hs = 0; hs < 2; ++hs) {
            const float* src = x + xB + (size_t)(oct * 8) * (NH * NW) + (hbase + hs) * NW + w;
            u32x4 pkv;
#pragma unroll
            for (int i = 0; i < 4; ++i)
                pkv[i] = pk2(src[(size_t)(2 * i) * (NH * NW)], src[(size_t)(2 * i + 1) * (NH * NW)]);
            const int loc  = hs * 64 + w;
            const int byte = loc * 128 + ((oct * 16) ^ ((loc & 7) << 4));
            *reinterpret_cast<u32x4*>(reinterpret_cast<char*>(Xs) + byte) = pkv;
        }
    }
    // ---- stage Patch: x[b, obase+o_l, hbase-1+hhi, ww] -> Patch[hhi][ww+1][o_l], bf16 ----
    {
        const int o_l = tid >> 4, i4 = (tid & 15) * 4;
        const float* xo = x + xB + (size_t)(obase + o_l) * (NH * NW);
#pragma unroll
        for (int hhi = 0; hhi < 4; ++hhi) {
            const int hh = hbase - 1 + hhi;
            float4 v = {0.f, 0.f, 0.f, 0.f};
            if (hh >= 0 && hh < NH) v = *reinterpret_cast<const float4*>(xo + hh * NW + i4);
            unsigned short* p = Patch + (hhi * 66 + i4 + 1) * 36 + o_l;
            p[0 * 36] = f2bf(v.x); p[1 * 36] = f2bf(v.y);
            p[2 * 36] = f2bf(v.z); p[3 * 36] = f2bf(v.w);
        }
        if (tid < 256) {   // zero w-halo columns (wwi = 0 and 65)
            const int hhi = tid >> 6, side = (tid >> 5) & 1, ol2 = tid & 31;
            Patch[(hhi * 66 + (side ? 65 : 0)) * 36 + ol2] = 0;
        }
    }
    // ---- bias: BiasL[(k*4+a)*32 + o_l] = b_gen[((obase+o_l)*4+a)*9 + k] ----
    for (int i = tid; i < 1152; i += 512) {
        const int k = i >> 7, a = (i >> 5) & 3, o_l = i & 31;
        BiasL[i] = b_gen[((obase + o_l) * 4 + a) * 9 + k];
    }
    writeW4(0);
    __syncthreads();

    // ---- x fragments -> registers (reused for all 36 taps) ----
    s16x8 xf[2][2];
#pragma unroll
    for (int nt = 0; nt < 2; ++nt) {
        const int loc = hrow * 64 + whalf * 32 + nt * 16 + c0;
#pragma unroll
        for (int kh2 = 0; kh2 < 2; ++kh2) {
            const int byte = loc * 128 + ((kh2 * 64 + q * 16) ^ ((loc & 7) << 4));
            xf[nt][kh2] = *reinterpret_cast<s16x8*>(reinterpret_cast<char*>(Xs) + byte);
        }
    }

    const int h = hbase + hrow;
    const float gy = -1.0f + (2.0f / 63.0f) * (float)h;
    float pe[8];
#pragma unroll
    for (int i = 0; i < 8; ++i) pe[i] = pos_enc[i];
    float attv[4][2];
#pragma unroll
    for (int a = 0; a < 4; ++a)
#pragma unroll
        for (int nt = 0; nt < 2; ++nt) {
            const float gx = -1.0f + (2.0f / 63.0f) * (float)(whalf * 32 + nt * 16 + c0);
            const float dx = gx - pe[2 * a], dy = gy - pe[2 * a + 1];
            attv[a][nt] = __expf(-(dx * dx + dy * dy));
        }

    const int o4 = ofrag * 16 + q * 4;     // this lane's o_local row base
    const int wrow = ofrag * 16 + c0;      // A-frag row index in Wb
    const int swz = (wrow & 7) << 4;
    // Patch byte: element ((hrow+kh)*66 + w_local+kw)*36 + o4, *2 bytes
    const int pb0 = ((hrow * 66 + whalf * 32 + c0) * 36 + o4) * 2;

    float outacc[2][4] = {};

#pragma unroll
    for (int k = 0; k < 9; ++k) {
        const int buf = k & 1;
        if (k < 8) loadW4(k + 1);           // issue-early (T14)
        float tsum[2][4] = {};
#pragma unroll
        for (int a = 0; a < 4; ++a) {
            const unsigned char* Wt = reinterpret_cast<const unsigned char*>(&Wb[buf][a][0]);
            const s16x8 wf0 = *reinterpret_cast<const s16x8*>(Wt + wrow * 128 + ((q * 16) ^ swz));
            const s16x8 wf1 = *reinterpret_cast<const s16x8*>(Wt + wrow * 128 + ((64 + q * 16) ^ swz));
            const f32x4 bb = *reinterpret_cast<const f32x4*>(BiasL + (k * 4 + a) * 32 + o4);
#pragma unroll
            for (int nt = 0; nt < 2; ++nt) {
                f32x4 acc = bb;
                acc = __builtin_amdgcn_mfma_f32_16x16x32_bf16(wf0, xf[nt][0], acc, 0, 0, 0);
                acc = __builtin_amdgcn_mfma_f32_16x16x32_bf16(wf1, xf[nt][1], acc, 0, 0, 0);
                const float at = attv[a][nt];
#pragma unroll
                for (int r = 0; r < 4; ++r)
                    tsum[nt][r] = fmaf(at, fmaxf(acc[r], 0.f), tsum[nt][r]);
            }
        }
        const int kh = k / 3, kw = k - 3 * kh;
#pragma unroll
        for (int nt = 0; nt < 2; ++nt) {
            const ushort4 pu = *reinterpret_cast<const ushort4*>(
                reinterpret_cast<const char*>(Patch) + pb0 + (kh * 66 + nt * 16 + kw) * 72);
            outacc[nt][0] = fmaf(tsum[nt][0], bf2f(pu.x), outacc[nt][0]);
            outacc[nt][1] = fmaf(tsum[nt][1], bf2f(pu.y), outacc[nt][1]);
            outacc[nt][2] = fmaf(tsum[nt][2], bf2f(pu.z), outacc[nt][2]);
            outacc[nt][3] = fmaf(tsum[nt][3], bf2f(pu.w), outacc[nt][3]);
        }
        if (k < 8) writeW4(buf ^ 1);        // write-late (T14)
        __syncthreads();
    }

    // ---- coalesced stores: col = w (lane&15) contiguous ----
#pragma unroll
    for (int nt = 0; nt < 2; ++nt) {
        const int wcol = whalf * 32 + nt * 16 + c0;
#pragma unroll
        for (int r = 0; r < 4; ++r) {
            const int o = obase + o4 + r;
            out[(((size_t)b * NO + o) * NH + h) * NW + wcol] = outacc[nt][r];
        }
    }
}

extern "C" void kernel_launch(void* const* d_in, const int* in_sizes, int n_in,
                              void* d_out, int out_size, void* d_ws, size_t ws_size,
                              hipStream_t stream) {
    const float* x       = (const float*)d_in[0];
    const float* w_gen   = (const float*)d_in[1];
    const float* b_gen   = (const float*)d_in[2];
    const float* pos_enc = (const float*)d_in[3];
    float* out = (float*)d_out;

    dim3 grid(NB * 32 * 2);   // 512 workgroups
    dim3 block(512);
    hipLaunchKernelGGL(acda_kernel, grid, block, 0, stream,
                       x, w_gen, b_gen, pos_enc, out);
}

// Round 12
// 29.567 us; speedup vs baseline: 1.8897x; 1.8897x over previous
//
#include <hip/hip_runtime.h>
#include <math.h>

constexpr int NB = 8, NC = 64, NO = 64, NH = 64, NW = 64;

using f32x4 = __attribute__((ext_vector_type(4))) float;
using s16x8 = __attribute__((ext_vector_type(8))) short;
using u32x4 = __attribute__((ext_vector_type(4))) unsigned int;

// packed f32x2 -> bf16x2 (RNE), v_cvt_pk_bf16_f32 (no builtin on gfx950)
__device__ __forceinline__ unsigned int pk2(float lo, float hi) {
    unsigned int r;
    asm("v_cvt_pk_bf16_f32 %0, %1, %2" : "=v"(r) : "v"(lo), "v"(hi));
    return r;
}
__device__ __forceinline__ unsigned short f2bf(float f) {
    unsigned u = __builtin_bit_cast(unsigned, f);
    return (unsigned short)((u + 0x7fffu + ((u >> 16) & 1u)) >> 16);
}
__device__ __forceinline__ float bf2f(unsigned short s) {
    unsigned u = ((unsigned)s) << 16;
    return __builtin_bit_cast(float, u);
}

// Grid 512 = b(8) x hquad(16) x osub(4). Block 1024 thr = 16 waves.
// Block tile: 4 h-rows x 64 w x 16 o (obase = osub*16). Wave (hrow = wv>>2, nt = wv&3)
// owns one 16x16 output tile; per tap: 2 MFMA (A = W rows=o, B = x cols=w).
// ALL inputs staged once (W-slice 72KB + Xs 32KB + Patch + bias = 124.6KB LDS, 1 blk/CU),
// ONE barrier, then 36 taps free-running (no mid-loop syncs).
// Registers tiny (~60 live) -> no spill at the 128-VGPR budget (R5/R7/R11 lesson).
__global__ __launch_bounds__(1024, 1)
void acda_kernel(const float* __restrict__ x, const float* __restrict__ w_gen,
                 const float* __restrict__ b_gen, const float* __restrict__ pos_enc,
                 float* __restrict__ out)
{
    __shared__ unsigned short Ws[16 * 36 * 64];   // 72 KB [o_l][t][c] bf16, XOR-swizzled
    __shared__ unsigned short Xs[256 * 64];       // 32 KB [loc][c]  bf16, XOR-swizzled
    __shared__ unsigned short Patch[6 * 66 * 20]; // 15.5 KB [hhi][wwi][o_l(16)+pad4] bf16
    __shared__ float BiasL[36 * 16];              // 2.3 KB [t][o_l]

    const int tid  = threadIdx.x;
    const int lane = tid & 63;
    const int wv   = tid >> 6;           // 0..15
    const int c0   = lane & 15, q = lane >> 4;
    const int hrow = wv >> 2, nt = wv & 3;

    const int bx    = blockIdx.x;
    const int osub  = bx & 3;
    const int hq    = (bx >> 2) & 15;
    const int b     = bx >> 6;
    const int hbase = hq * 4;
    const int obase = osub * 16;
    const size_t xB = (size_t)b * NC * NH * NW;

    // ---- stage W-slice: w_gen[(obase+o_l)*36 + t][c] f32 -> Ws[o_l][t][c] bf16 swz ----
    // 4608 units of 16B (o_l 16 x t 36 x cseg 8)
    for (int u = tid; u < 4608; u += 1024) {
        const int o_l = u / 288;
        const int r   = u - o_l * 288;
        const int t   = r >> 3, cseg = r & 7;
        const float* src = w_gen + ((size_t)(obase + o_l) * 36 + t) * NC + cseg * 8;
        const float4 v0 = *reinterpret_cast<const float4*>(src);
        const float4 v1 = *reinterpret_cast<const float4*>(src + 4);
        u32x4 pk;
        pk[0] = pk2(v0.x, v0.y); pk[1] = pk2(v0.z, v0.w);
        pk[2] = pk2(v1.x, v1.y); pk[3] = pk2(v1.z, v1.w);
        const int byte = (o_l * 36 + t) * 128 + ((cseg * 16) ^ ((o_l & 7) << 4));
        *reinterpret_cast<u32x4*>(reinterpret_cast<char*>(Ws) + byte) = pk;
    }
    // ---- stage Xs: x[b,c,hbase+hs,w] -> Xs[loc = hs*64+w][c] bf16 swz ----
    {
        const int w = lane, hs = wv & 3, op = wv >> 2;
#pragma unroll
        for (int oc2 = 0; oc2 < 2; ++oc2) {
            const int oct = op * 2 + oc2;
            const float* src = x + xB + (size_t)(oct * 8) * (NH * NW) + (hbase + hs) * NW + w;
            u32x4 pkv;
#pragma unroll
            for (int i = 0; i < 4; ++i)
                pkv[i] = pk2(src[(size_t)(2 * i) * (NH * NW)], src[(size_t)(2 * i + 1) * (NH * NW)]);
            const int loc  = hs * 64 + w;
            const int byte = loc * 128 + ((oct * 16) ^ ((loc & 7) << 4));
            *reinterpret_cast<u32x4*>(reinterpret_cast<char*>(Xs) + byte) = pkv;
        }
    }
    // ---- stage Patch: x[b,obase+o_l,hbase-1+hhi,w] -> Patch[hhi][w+1][o_l] bf16 ----
    {
        const int o_l = tid >> 6, w = tid & 63;
        const float* xo = x + xB + (size_t)(obase + o_l) * (NH * NW);
#pragma unroll
        for (int hhi = 0; hhi < 6; ++hhi) {
            const int hh = hbase - 1 + hhi;
            const float v = (hh >= 0 && hh < NH) ? xo[hh * NW + w] : 0.0f;
            Patch[(hhi * 66 + w + 1) * 20 + o_l] = f2bf(v);
            if (w < 2) Patch[(hhi * 66 + (w ? 65 : 0)) * 20 + o_l] = 0;
        }
    }
    // ---- stage bias: BiasL[t*16 + o_l] = b_gen[(obase+o_l)*36 + t] ----
    for (int i = tid; i < 576; i += 1024) {
        const int t = i >> 4, o_l = i & 15;
        BiasL[i] = b_gen[(obase + o_l) * 36 + t];
    }
    __syncthreads();   // the only barrier

    // ---- x fragments for this wave's tile ----
    s16x8 xf[2];
    {
        const int loc = hrow * 64 + nt * 16 + c0;
#pragma unroll
        for (int kh2 = 0; kh2 < 2; ++kh2) {
            const int byte = loc * 128 + ((kh2 * 64 + q * 16) ^ ((loc & 7) << 4));
            xf[kh2] = *reinterpret_cast<s16x8*>(reinterpret_cast<char*>(Xs) + byte);
        }
    }

    const float gy = -1.0f + (2.0f / 63.0f) * (float)(hbase + hrow);
    const float gx = -1.0f + (2.0f / 63.0f) * (float)(nt * 16 + c0);

    // W-frag byte offsets for this lane (row o_l = c0)
    const int wswz = (c0 & 7) << 4;
    const int wrowbase = c0 * 36 * 128;

    float outacc[4] = {0.f, 0.f, 0.f, 0.f};

#pragma unroll
    for (int a = 0; a < 4; ++a) {
        const float dx = gx - pos_enc[2 * a], dy = gy - pos_enc[2 * a + 1];
        const float att = __expf(-(dx * dx + dy * dy));
#pragma unroll
        for (int k = 0; k < 9; ++k) {
            const int t  = a * 9 + k;
            const int kh = k / 3, kw = k - 3 * kh;
            const char* wr = reinterpret_cast<const char*>(Ws) + wrowbase + t * 128;
            const s16x8 wf0 = *reinterpret_cast<const s16x8*>(wr + ((q * 16) ^ wswz));
            const s16x8 wf1 = *reinterpret_cast<const s16x8*>(wr + ((64 + q * 16) ^ wswz));
            const f32x4 bb = *reinterpret_cast<const f32x4*>(BiasL + t * 16 + q * 4);
            f32x4 acc = bb;
            acc = __builtin_amdgcn_mfma_f32_16x16x32_bf16(wf0, xf[0], acc, 0, 0, 0);
            acc = __builtin_amdgcn_mfma_f32_16x16x32_bf16(wf1, xf[1], acc, 0, 0, 0);
            const ushort4 pu = *reinterpret_cast<const ushort4*>(
                reinterpret_cast<const char*>(Patch) +
                (((hrow + kh) * 66 + nt * 16 + c0 + kw) * 20 + q * 4) * 2);
            outacc[0] = fmaf(fmaxf(acc[0], 0.f) * att, bf2f(pu.x), outacc[0]);
            outacc[1] = fmaf(fmaxf(acc[1], 0.f) * att, bf2f(pu.y), outacc[1]);
            outacc[2] = fmaf(fmaxf(acc[2], 0.f) * att, bf2f(pu.z), outacc[2]);
            outacc[3] = fmaf(fmaxf(acc[3], 0.f) * att, bf2f(pu.w), outacc[3]);
        }
    }

    // ---- stores: 16 consecutive w per 16-lane group ----
    const int h = hbase + hrow, wcol = nt * 16 + c0;
#pragma unroll
    for (int r = 0; r < 4; ++r) {
        const int o = obase + q * 4 + r;
        out[(((size_t)b * NO + o) * NH + h) * NW + wcol] = outacc[r];
    }
}

extern "C" void kernel_launch(void* const* d_in, const int* in_sizes, int n_in,
                              void* d_out, int out_size, void* d_ws, size_t ws_size,
                              hipStream_t stream) {
    const float* x       = (const float*)d_in[0];
    const float* w_gen   = (const float*)d_in[1];
    const float* b_gen   = (const float*)d_in[2];
    const float* pos_enc = (const float*)d_in[3];
    float* out = (float*)d_out;

    dim3 grid(NB * 16 * 4);   // 512 workgroups
    dim3 block(1024);
    hipLaunchKernelGGL(acda_kernel, grid, block, 0, stream,
                       x, w_gen, b_gen, pos_enc, out);
}

// Round 13
// 26.216 us; speedup vs baseline: 2.1312x; 1.1278x over previous
//
#include <hip/hip_runtime.h>
#include <math.h>

constexpr int NB = 8, NC = 64, NO = 64, NH = 64, NW = 64;

using f32x4 = __attribute__((ext_vector_type(4))) float;
using s16x8 = __attribute__((ext_vector_type(8))) short;
using u32x4 = __attribute__((ext_vector_type(4))) unsigned int;

// packed f32x2 -> bf16x2 (RNE), v_cvt_pk_bf16_f32 (no builtin on gfx950)
__device__ __forceinline__ unsigned int pk2(float lo, float hi) {
    unsigned int r;
    asm("v_cvt_pk_bf16_f32 %0, %1, %2" : "=v"(r) : "v"(lo), "v"(hi));
    return r;
}
__device__ __forceinline__ unsigned short f2bf(float f) {
    unsigned u = __builtin_bit_cast(unsigned, f);
    return (unsigned short)((u + 0x7fffu + ((u >> 16) & 1u)) >> 16);
}
__device__ __forceinline__ float bf2f(unsigned short s) {
    unsigned u = ((unsigned)s) << 16;
    return __builtin_bit_cast(float, u);
}

// Grid 256 = b(8) x hoct(8) x osub(4) -> EXACTLY 1 block/CU round. Block 1024 thr = 16 waves.
// Block tile: 8 h-rows x 64 w x 16 o (obase = osub*16). Wave: hrow = wv>>1, whalf = wv&1,
// 2 n-tiles of 16 w -> each W-frag/bias LDS read feeds 2 MFMA pairs (amortized 2x vs R12).
// MFMA A = W (rows=o), B = x (cols=w). D: row(o)=q*4+reg, col(w)=c0 -> coalesced stores.
// LDS 138.3 KB: arena (Xs 64KB -> xf regs -> Patch 26.4KB) + Ws 72KB + bias. 1 blk/CU, 4 w/SIMD.
// Registers ~70 live -> no spill at the 128-VGPR budget (R5/R7/R11 lesson).
__global__ __launch_bounds__(1024, 1)
void acda_kernel(const float* __restrict__ x, const float* __restrict__ w_gen,
                 const float* __restrict__ b_gen, const float* __restrict__ pos_enc,
                 float* __restrict__ out)
{
    __shared__ __align__(16) unsigned char arena[65536];  // Xs [512 loc][64c] bf16 swz, then Patch [10][66][20] bf16
    __shared__ unsigned short Ws[16 * 36 * 64];           // 72 KB [o_l][t][c] bf16, XOR-swizzled
    __shared__ float BiasL[36 * 16];                      // 2.3 KB [t][o_l]

    const int tid  = threadIdx.x;
    const int lane = tid & 63;
    const int wv   = tid >> 6;           // 0..15
    const int c0   = lane & 15, q = lane >> 4;
    const int hrow = wv >> 1, whalf = wv & 1;

    const int bx    = blockIdx.x;
    const int osub  = bx & 3;
    const int hoct  = (bx >> 2) & 7;
    const int b     = bx >> 5;
    const int hbase = hoct * 8;
    const int obase = osub * 16;
    const size_t xB = (size_t)b * NC * NH * NW;

    // ---- stage Ws first (largest global chunk, loads overlap the rest of the prologue) ----
    // w_gen[(obase+o_l)*36 + t][c] f32 -> Ws[o_l][t][c] bf16 swz. 4608 units of 16B.
    for (int u = tid; u < 4608; u += 1024) {
        const int o_l = u / 288;
        const int r   = u - o_l * 288;
        const int t   = r >> 3, cseg = r & 7;
        const float* src = w_gen + ((size_t)(obase + o_l) * 36 + t) * NC + cseg * 8;
        const float4 v0 = *reinterpret_cast<const float4*>(src);
        const float4 v1 = *reinterpret_cast<const float4*>(src + 4);
        u32x4 pk;
        pk[0] = pk2(v0.x, v0.y); pk[1] = pk2(v0.z, v0.w);
        pk[2] = pk2(v1.x, v1.y); pk[3] = pk2(v1.z, v1.w);
        const int byte = (o_l * 36 + t) * 128 + ((cseg * 16) ^ ((o_l & 7) << 4));
        *reinterpret_cast<u32x4*>(reinterpret_cast<char*>(Ws) + byte) = pk;
    }
    // ---- stage Xs into arena: x[b,c,hbase+hs,w] -> [loc = hs*64+w][c] bf16 swz ----
    {
        const int w = lane;
#pragma unroll
        for (int i = 0; i < 4; ++i) {
            const int pair = wv * 4 + i;          // 64 (hs, oct) pairs
            const int hs = pair >> 3, oct = pair & 7;
            const float* src = x + xB + (size_t)(oct * 8) * (NH * NW) + (hbase + hs) * NW + w;
            u32x4 pkv;
#pragma unroll
            for (int j = 0; j < 4; ++j)
                pkv[j] = pk2(src[(size_t)(2 * j) * (NH * NW)], src[(size_t)(2 * j + 1) * (NH * NW)]);
            const int loc  = hs * 64 + w;
            const int byte = loc * 128 + ((oct * 16) ^ ((loc & 7) << 4));
            *reinterpret_cast<u32x4*>(arena + byte) = pkv;
        }
    }
    // ---- stage bias: BiasL[t*16 + o_l] = b_gen[(obase+o_l)*36 + t] ----
    for (int i = tid; i < 576; i += 1024) {
        const int t = i >> 4, o_l = i & 15;
        BiasL[i] = b_gen[(obase + o_l) * 36 + t];
    }
    __syncthreads();   // Xs ready

    // ---- x fragments: 2 n-tiles ----
    s16x8 xf[2][2];
#pragma unroll
    for (int nt = 0; nt < 2; ++nt) {
        const int loc = hrow * 64 + whalf * 32 + nt * 16 + c0;
#pragma unroll
        for (int kh2 = 0; kh2 < 2; ++kh2) {
            const int byte = loc * 128 + ((kh2 * 64 + q * 16) ^ ((loc & 7) << 4));
            xf[nt][kh2] = *reinterpret_cast<s16x8*>(arena + byte);
        }
    }
    __syncthreads();   // all Xs reads done; arena becomes Patch

    // ---- stage Patch: x[b,obase+o_l,hbase-1+hhi,w] -> Patch[hhi][w+1][o_l] bf16 ----
    unsigned short* Patch = reinterpret_cast<unsigned short*>(arena);
    {
        const int o_l = tid >> 6, w = tid & 63;
        const float* xo = x + xB + (size_t)(obase + o_l) * (NH * NW);
#pragma unroll
        for (int hhi = 0; hhi < 10; ++hhi) {
            const int hh = hbase - 1 + hhi;
            const float v = (hh >= 0 && hh < NH) ? xo[hh * NW + w] : 0.0f;
            Patch[(hhi * 66 + w + 1) * 20 + o_l] = f2bf(v);
            if (w < 2) Patch[(hhi * 66 + (w ? 65 : 0)) * 20 + o_l] = 0;
        }
    }
    __syncthreads();   // Ws, Patch, BiasL ready

    const float gy = -1.0f + (2.0f / 63.0f) * (float)(hbase + hrow);
    float gxn[2];
#pragma unroll
    for (int nt = 0; nt < 2; ++nt)
        gxn[nt] = -1.0f + (2.0f / 63.0f) * (float)(whalf * 32 + nt * 16 + c0);

    const int wswz = (c0 & 7) << 4;
    const char* wrowp = reinterpret_cast<const char*>(Ws) + c0 * (36 * 128);

    float outacc[2][4] = {};

#pragma unroll
    for (int a = 0; a < 4; ++a) {
        float attn[2];
#pragma unroll
        for (int nt = 0; nt < 2; ++nt) {
            const float dx = gxn[nt] - pos_enc[2 * a], dy = gy - pos_enc[2 * a + 1];
            attn[nt] = __expf(-(dx * dx + dy * dy));
        }
#pragma unroll
        for (int k = 0; k < 9; ++k) {
            const int t  = a * 9 + k;
            const int kh = k / 3, kw = k - 3 * kh;
            const s16x8 wf0 = *reinterpret_cast<const s16x8*>(wrowp + t * 128 + ((q * 16) ^ wswz));
            const s16x8 wf1 = *reinterpret_cast<const s16x8*>(wrowp + t * 128 + ((64 + q * 16) ^ wswz));
            const f32x4 bb  = *reinterpret_cast<const f32x4*>(BiasL + t * 16 + q * 4);
#pragma unroll
            for (int nt = 0; nt < 2; ++nt) {
                f32x4 acc = bb;
                acc = __builtin_amdgcn_mfma_f32_16x16x32_bf16(wf0, xf[nt][0], acc, 0, 0, 0);
                acc = __builtin_amdgcn_mfma_f32_16x16x32_bf16(wf1, xf[nt][1], acc, 0, 0, 0);
                const ushort4 pu = *reinterpret_cast<const ushort4*>(
                    reinterpret_cast<const char*>(Patch) +
                    (((hrow + kh) * 66 + whalf * 32 + nt * 16 + c0 + kw) * 20 + q * 4) * 2);
                const float at = attn[nt];
                outacc[nt][0] = fmaf(fmaxf(acc[0], 0.f) * at, bf2f(pu.x), outacc[nt][0]);
                outacc[nt][1] = fmaf(fmaxf(acc[1], 0.f) * at, bf2f(pu.y), outacc[nt][1]);
                outacc[nt][2] = fmaf(fmaxf(acc[2], 0.f) * at, bf2f(pu.z), outacc[nt][2]);
                outacc[nt][3] = fmaf(fmaxf(acc[3], 0.f) * at, bf2f(pu.w), outacc[nt][3]);
            }
        }
    }

    // ---- coalesced stores: 16 consecutive w per 16-lane group ----
    const int h = hbase + hrow;
#pragma unroll
    for (int nt = 0; nt < 2; ++nt) {
        const int wcol = whalf * 32 + nt * 16 + c0;
#pragma unroll
        for (int r = 0; r < 4; ++r) {
            const int o = obase + q * 4 + r;
            out[(((size_t)b * NO + o) * NH + h) * NW + wcol] = outacc[nt][r];
        }
    }
}

extern "C" void kernel_launch(void* const* d_in, const int* in_sizes, int n_in,
                              void* d_out, int out_size, void* d_ws, size_t ws_size,
                              hipStream_t stream) {
    const float* x       = (const float*)d_in[0];
    const float* w_gen   = (const float*)d_in[1];
    const float* b_gen   = (const float*)d_in[2];
    const float* pos_enc = (const float*)d_in[3];
    float* out = (float*)d_out;

    dim3 grid(NB * 8 * 4);   // 256 workgroups = 1 per CU
    dim3 block(1024);
    hipLaunchKernelGGL(acda_kernel, grid, block, 0, stream,
                       x, w_gen, b_gen, pos_enc, out);
}

// Round 14
// 25.876 us; speedup vs baseline: 2.1592x; 1.0131x over previous
//
#include <hip/hip_runtime.h>
#include <math.h>

constexpr int NB = 8, NC = 64, NO = 64, NH = 64, NW = 64;

using f32x4 = __attribute__((ext_vector_type(4))) float;
using s16x8 = __attribute__((ext_vector_type(8))) short;
using u32x4 = __attribute__((ext_vector_type(4))) unsigned int;

// packed f32x2 -> bf16x2 (RNE), v_cvt_pk_bf16_f32 (no builtin on gfx950)
__device__ __forceinline__ unsigned int pk2(float lo, float hi) {
    unsigned int r;
    asm("v_cvt_pk_bf16_f32 %0, %1, %2" : "=v"(r) : "v"(lo), "v"(hi));
    return r;
}
__device__ __forceinline__ unsigned short f2bf(float f) {
    unsigned u = __builtin_bit_cast(unsigned, f);
    return (unsigned short)((u + 0x7fffu + ((u >> 16) & 1u)) >> 16);
}
__device__ __forceinline__ float bf2f(unsigned short s) {
    unsigned u = ((unsigned)s) << 16;
    return __builtin_bit_cast(float, u);
}

// Grid 256 = b(8) x hoct(8) x osub(4) -> exactly 1 block/CU. Block 512 thr = 8 waves.
// Block tile: 8 h-rows x 64 w x 16 o. Wave wv = hrow owns the full row: 4 n-tiles of 16 w
// -> each W-frag/bias LDS read feeds 4 MFMA pairs (2x better amortization than R13).
// k-OUTER / a-INNER: tsum[k] accumulated over atoms, ONE patch read per (k,nt) (4x fewer).
// MFMA A = W (rows=o), B = x (cols=w). D: row(o)=q*4+reg, col(w)=c0 -> coalesced stores.
// LDS 138.3 KB (arena Xs 64KB -> xf regs -> Patch 26.4KB; Ws 72KB; bias 2.3KB), 1 blk/CU.
// launch_bounds(512,1): 2 waves/SIMD floor -> 256-VGPR budget; live set ~110 -> no spill
// (R5/R7/R11 spill class avoided).
__global__ __launch_bounds__(512, 1)
void acda_kernel(const float* __restrict__ x, const float* __restrict__ w_gen,
                 const float* __restrict__ b_gen, const float* __restrict__ pos_enc,
                 float* __restrict__ out)
{
    __shared__ __align__(16) unsigned char arena[65536];  // Xs [512 loc][64c] bf16 swz -> Patch [10][66][20] bf16
    __shared__ unsigned short Ws[16 * 36 * 64];           // 72 KB [o_l][t][c] bf16, XOR-swizzled
    __shared__ float BiasL[36 * 16];                      // 2.3 KB [t][o_l]

    const int tid  = threadIdx.x;
    const int lane = tid & 63;
    const int wv   = tid >> 6;           // 0..7 = hrow
    const int c0   = lane & 15, q = lane >> 4;
    const int hrow = wv;

    const int bx    = blockIdx.x;
    const int osub  = bx & 3;
    const int hoct  = (bx >> 2) & 7;
    const int b     = bx >> 5;
    const int hbase = hoct * 8;
    const int obase = osub * 16;
    const size_t xB = (size_t)b * NC * NH * NW;

    // ---- stage Ws: w_gen[(obase+o_l)*36 + t][c] f32 -> Ws[o_l][t][c] bf16 swz (4608 x 16B) ----
    for (int u = tid; u < 4608; u += 512) {
        const int o_l = u / 288;
        const int r   = u - o_l * 288;
        const int t   = r >> 3, cseg = r & 7;
        const float* src = w_gen + ((size_t)(obase + o_l) * 36 + t) * NC + cseg * 8;
        const float4 v0 = *reinterpret_cast<const float4*>(src);
        const float4 v1 = *reinterpret_cast<const float4*>(src + 4);
        u32x4 pk;
        pk[0] = pk2(v0.x, v0.y); pk[1] = pk2(v0.z, v0.w);
        pk[2] = pk2(v1.x, v1.y); pk[3] = pk2(v1.z, v1.w);
        const int byte = (o_l * 36 + t) * 128 + ((cseg * 16) ^ ((o_l & 7) << 4));
        *reinterpret_cast<u32x4*>(reinterpret_cast<char*>(Ws) + byte) = pk;
    }
    // ---- stage Xs into arena: x[b,c,hbase+hs,w] -> [loc = hs*64+w][c] bf16 swz ----
    {
        const int w = lane;
#pragma unroll
        for (int i = 0; i < 8; ++i) {
            const int pair = wv * 8 + i;          // 64 (hs, oct) pairs
            const int hs = pair >> 3, oct = pair & 7;
            const float* src = x + xB + (size_t)(oct * 8) * (NH * NW) + (hbase + hs) * NW + w;
            u32x4 pkv;
#pragma unroll
            for (int j = 0; j < 4; ++j)
                pkv[j] = pk2(src[(size_t)(2 * j) * (NH * NW)], src[(size_t)(2 * j + 1) * (NH * NW)]);
            const int loc  = hs * 64 + w;
            const int byte = loc * 128 + ((oct * 16) ^ ((loc & 7) << 4));
            *reinterpret_cast<u32x4*>(arena + byte) = pkv;
        }
    }
    // ---- stage bias: BiasL[t*16 + o_l] = b_gen[(obase+o_l)*36 + t] ----
    for (int i = tid; i < 576; i += 512) {
        const int t = i >> 4, o_l = i & 15;
        BiasL[i] = b_gen[(obase + o_l) * 36 + t];
    }
    __syncthreads();   // Xs ready

    // ---- x fragments: 4 n-tiles (full h-row per wave) ----
    s16x8 xf[4][2];
#pragma unroll
    for (int nt = 0; nt < 4; ++nt) {
        const int loc = hrow * 64 + nt * 16 + c0;
#pragma unroll
        for (int kh2 = 0; kh2 < 2; ++kh2) {
            const int byte = loc * 128 + ((kh2 * 64 + q * 16) ^ ((loc & 7) << 4));
            xf[nt][kh2] = *reinterpret_cast<s16x8*>(arena + byte);
        }
    }
    __syncthreads();   // all Xs reads done; arena becomes Patch

    // ---- stage Patch: x[b,obase+o_l,hbase-1+hhi,w] -> Patch[hhi][w+1][o_l] bf16 ----
    unsigned short* Patch = reinterpret_cast<unsigned short*>(arena);
    {
        const int o_l = tid >> 5, w2 = (tid & 31) * 2;
        const float* xo = x + xB + (size_t)(obase + o_l) * (NH * NW);
#pragma unroll
        for (int hhi = 0; hhi < 10; ++hhi) {
            const int hh = hbase - 1 + hhi;
            float2 v = {0.f, 0.f};
            if (hh >= 0 && hh < NH) v = *reinterpret_cast<const float2*>(xo + hh * NW + w2);
            Patch[(hhi * 66 + w2 + 1) * 20 + o_l] = f2bf(v.x);
            Patch[(hhi * 66 + w2 + 2) * 20 + o_l] = f2bf(v.y);
        }
    }
    if (tid < 320) {   // zero halo columns wwi = 0, 65
        const int hhi = tid >> 5, side = (tid >> 4) & 1, o_l = tid & 15;
        Patch[(hhi * 66 + (side ? 65 : 0)) * 20 + o_l] = 0;
    }
    __syncthreads();   // Ws, Patch, BiasL ready

    // ---- attention attv[a][nt] ----
    const float gy = -1.0f + (2.0f / 63.0f) * (float)(hbase + hrow);
    float attv[4][4];
#pragma unroll
    for (int a = 0; a < 4; ++a) {
        const float px = pos_enc[2 * a], py = pos_enc[2 * a + 1];
#pragma unroll
        for (int nt = 0; nt < 4; ++nt) {
            const float gx = -1.0f + (2.0f / 63.0f) * (float)(nt * 16 + c0);
            const float dx = gx - px, dy = gy - py;
            attv[a][nt] = __expf(-(dx * dx + dy * dy));
        }
    }

    const int wswz = (c0 & 7) << 4;
    const char* wrowp = reinterpret_cast<const char*>(Ws) + c0 * (36 * 128);

    float outacc[4][4] = {};

#pragma unroll
    for (int k = 0; k < 9; ++k) {
        float tsum[4][4] = {};
#pragma unroll
        for (int a = 0; a < 4; ++a) {
            const int t = a * 9 + k;
            const s16x8 wf0 = *reinterpret_cast<const s16x8*>(wrowp + t * 128 + ((q * 16) ^ wswz));
            const s16x8 wf1 = *reinterpret_cast<const s16x8*>(wrowp + t * 128 + ((64 + q * 16) ^ wswz));
            const f32x4 bb  = *reinterpret_cast<const f32x4*>(BiasL + t * 16 + q * 4);
#pragma unroll
            for (int nt = 0; nt < 4; ++nt) {
                f32x4 acc = bb;
                acc = __builtin_amdgcn_mfma_f32_16x16x32_bf16(wf0, xf[nt][0], acc, 0, 0, 0);
                acc = __builtin_amdgcn_mfma_f32_16x16x32_bf16(wf1, xf[nt][1], acc, 0, 0, 0);
                const float at = attv[a][nt];
#pragma unroll
                for (int r = 0; r < 4; ++r)
                    tsum[nt][r] = fmaf(at, fmaxf(acc[r], 0.f), tsum[nt][r]);
            }
        }
        const int kh = k / 3, kw = k - 3 * kh;
#pragma unroll
        for (int nt = 0; nt < 4; ++nt) {
            const ushort4 pu = *reinterpret_cast<const ushort4*>(
                reinterpret_cast<const char*>(Patch) +
                (((hrow + kh) * 66 + nt * 16 + c0 + kw) * 20 + q * 4) * 2);
            outacc[nt][0] = fmaf(tsum[nt][0], bf2f(pu.x), outacc[nt][0]);
            outacc[nt][1] = fmaf(tsum[nt][1], bf2f(pu.y), outacc[nt][1]);
            outacc[nt][2] = fmaf(tsum[nt][2], bf2f(pu.z), outacc[nt][2]);
            outacc[nt][3] = fmaf(tsum[nt][3], bf2f(pu.w), outacc[nt][3]);
        }
    }

    // ---- coalesced stores: 16 consecutive w per 16-lane group ----
    const int h = hbase + hrow;
#pragma unroll
    for (int nt = 0; nt < 4; ++nt) {
        const int wcol = nt * 16 + c0;
#pragma unroll
        for (int r = 0; r < 4; ++r) {
            const int o = obase + q * 4 + r;
            out[(((size_t)b * NO + o) * NH + h) * NW + wcol] = outacc[nt][r];
        }
    }
}

extern "C" void kernel_launch(void* const* d_in, const int* in_sizes, int n_in,
                              void* d_out, int out_size, void* d_ws, size_t ws_size,
                              hipStream_t stream) {
    const float* x       = (const float*)d_in[0];
    const float* w_gen   = (const float*)d_in[1];
    const float* b_gen   = (const float*)d_in[2];
    const float* pos_enc = (const float*)d_in[3];
    float* out = (float*)d_out;

    dim3 grid(NB * 8 * 4);   // 256 workgroups = 1 per CU
    dim3 block(512);
    hipLaunchKernelGGL(acda_kernel, grid, block, 0, stream,
                       x, w_gen, b_gen, pos_enc, out);
}